// Round 1
// baseline (1309.563 us; speedup 1.0000x reference)
//
#include <hip/hip_runtime.h>
#include <stdint.h>

#define NBATCH   8
#define NA       1047552
#define PRE_NMS  6000
#define NPROP    1000
#define BINS     2048
#define HB       64        // histogram blocks per batch
#define CAND_CAP 8192
#define PAIR_CAP 8192
#define NMS_THR  0.7f

// ---- workspace layout (bytes) ----
// hist      : NBATCH*HB*BINS*4 = 4,194,304
// ccnt/pcnt/cbin : 3*NBATCH*4  = 96   (at 4,194,304)
// cand      : NBATCH*CAND_CAP*8 = 524,288   (at 4,194,560)
// boxes     : NBATCH*PRE_NMS*16 = 768,000   (at 4,718,848)
// pairs     : NBATCH*PAIR_CAP*4 = 262,144   (at 5,486,848)
// total ~ 5,748,992
#define HIST_BYTES  ((size_t)NBATCH * HB * BINS * 4)
#define CAND_OFF    (HIST_BYTES + 256)
#define BOXES_OFF   (CAND_OFF + (size_t)NBATCH * CAND_CAP * 8)
#define PAIRS_OFF   (BOXES_OFF + (size_t)NBATCH * PRE_NMS * 16)
#define WS_NEEDED   (PAIRS_OFF + (size_t)NBATCH * PAIR_CAP * 4)

__device__ __forceinline__ unsigned score_bin(float s) {
    int b = (int)(s * (float)BINS);
    if (b < 0) b = 0;
    if (b > BINS - 1) b = BINS - 1;
    return (unsigned)b;
}

// K1: per-block private histogram of scores[b, :, 1]; write full private hist (no zeroing needed).
__global__ __launch_bounds__(256) void k_hist(const float* __restrict__ scores,
                                              uint32_t* __restrict__ hist) {
    __shared__ uint32_t lh[BINS];
    const int b = blockIdx.y;
    for (int t = threadIdx.x; t < BINS; t += blockDim.x) lh[t] = 0;
    __syncthreads();
    const float4* s4 = reinterpret_cast<const float4*>(scores) + (size_t)b * (NA / 2);
    const int n4 = NA / 2;
    const int stride = gridDim.x * blockDim.x;
    for (int i = blockIdx.x * blockDim.x + threadIdx.x; i < n4; i += stride) {
        float4 v = s4[i];  // scores for anchors 2i (.y) and 2i+1 (.w); .x/.z are class-0
        atomicAdd(&lh[score_bin(v.y)], 1u);
        atomicAdd(&lh[score_bin(v.w)], 1u);
    }
    __syncthreads();
    uint32_t* gh = hist + ((size_t)b * HB + blockIdx.x) * BINS;
    for (int t = threadIdx.x; t < BINS; t += blockDim.x) gh[t] = lh[t];
}

// K2: reduce private hists, suffix-scan from top to find threshold bin C (cum >= PRE_NMS).
__global__ __launch_bounds__(256) void k_thresh(const uint32_t* __restrict__ hist,
                                                uint32_t* __restrict__ cbin) {
    __shared__ uint32_t hsum[BINS];
    const int b = blockIdx.x;
    const uint32_t* hb = hist + (size_t)b * HB * BINS;
    for (int t = threadIdx.x; t < BINS; t += blockDim.x) {
        uint32_t s = 0;
        for (int k = 0; k < HB; ++k) s += hb[(size_t)k * BINS + t];
        hsum[t] = s;
    }
    __syncthreads();
    if (threadIdx.x == 0) {
        uint32_t cum = 0; int c = 0;
        for (int bin = BINS - 1; bin >= 0; --bin) {
            cum += hsum[bin];
            if (cum >= PRE_NMS) { c = bin; break; }
        }
        cbin[b] = (uint32_t)c;
    }
}

// K3: gather keys for all elements with bin >= C.  key = (score_bits<<32) | ~index
__global__ __launch_bounds__(256) void k_gather(const float* __restrict__ scores,
                                                const uint32_t* __restrict__ cbin,
                                                uint32_t* __restrict__ ccnt,
                                                uint64_t* __restrict__ cand) {
    const int b = blockIdx.y;
    const unsigned C = cbin[b];
    const float4* s4 = reinterpret_cast<const float4*>(scores) + (size_t)b * (NA / 2);
    const int n4 = NA / 2;
    const int stride = gridDim.x * blockDim.x;
    uint64_t* cb = cand + (size_t)b * CAND_CAP;
    for (int i = blockIdx.x * blockDim.x + threadIdx.x; i < n4; i += stride) {
        float4 v = s4[i];
        float  sc[2] = { v.y, v.w };
        #pragma unroll
        for (int h = 0; h < 2; ++h) {
            if (score_bin(sc[h]) >= C) {
                unsigned idx = 2u * (unsigned)i + (unsigned)h;
                unsigned pos = atomicAdd(&ccnt[b], 1u);
                if (pos < CAND_CAP)
                    cb[pos] = ((uint64_t)__float_as_uint(sc[h]) << 32) | (uint32_t)(~idx);
            }
        }
    }
}

// K4: per-batch bitonic sort (ascending on ~key == descending on key), then decode top-6000 boxes.
__global__ __launch_bounds__(1024) void k_sort_boxes(const uint64_t* __restrict__ cand,
                                                     const uint32_t* __restrict__ ccnt,
                                                     const float* __restrict__ deltas,
                                                     const float* __restrict__ anchors,
                                                     float4* __restrict__ boxesOut) {
    __shared__ uint64_t s[CAND_CAP];  // 64 KB
    const int b = blockIdx.x;
    unsigned cnt = ccnt[b]; if (cnt > CAND_CAP) cnt = CAND_CAP;
    const uint64_t* cb = cand + (size_t)b * CAND_CAP;
    for (int i = threadIdx.x; i < CAND_CAP; i += 1024)
        s[i] = (i < (int)cnt) ? ~cb[i] : ~0ull;   // pad sorts last
    __syncthreads();
    for (unsigned k = 2; k <= CAND_CAP; k <<= 1) {
        for (unsigned j = k >> 1; j > 0; j >>= 1) {
            for (unsigned i = threadIdx.x; i < CAND_CAP; i += 1024) {
                unsigned ixj = i ^ j;
                if (ixj > i) {
                    uint64_t a = s[i], c = s[ixj];
                    bool up = ((i & k) == 0);
                    if ((a > c) == up) { s[i] = c; s[ixj] = a; }
                }
            }
            __syncthreads();
        }
    }
    // decode boxes for ranks 0..PRE_NMS-1
    const float4* anc = reinterpret_cast<const float4*>(anchors);
    const float4* del = reinterpret_cast<const float4*>(deltas) + (size_t)b * NA;
    for (int r = threadIdx.x; r < PRE_NMS; r += 1024) {
        float4 o = make_float4(0.f, 0.f, 0.f, 0.f);
        if (r < (int)cnt) {
            unsigned idx = (uint32_t)s[r];   // low 32 of ~key == index
            float4 a = anc[idx];
            float4 d = del[idx];
            float h = a.z - a.x, w = a.w - a.y;
            float cy = a.x + 0.5f * h + (d.x * 0.1f) * h;
            float cx = a.y + 0.5f * w + (d.y * 0.1f) * w;
            h = h * expf(d.z * 0.2f);
            w = w * expf(d.w * 0.2f);
            float y1 = cy - 0.5f * h, x1 = cx - 0.5f * w;
            float y2 = y1 + h,        x2 = x1 + w;
            o.x = fminf(fmaxf(y1, 0.f), 1.f);
            o.y = fminf(fmaxf(x1, 0.f), 1.f);
            o.z = fminf(fmaxf(y2, 0.f), 1.f);
            o.w = fminf(fmaxf(x2, 0.f), 1.f);
        }
        boxesOut[(size_t)b * PRE_NMS + r] = o;
    }
}

// K5: brute-force sparse overlap pairs (i<j, IoU>thr) over 64x64 tiles.
__global__ __launch_bounds__(64) void k_pairs(const float4* __restrict__ boxes,
                                              uint32_t* __restrict__ pcnt,
                                              uint32_t* __restrict__ pairs) {
    const int tj = blockIdx.x, ti = blockIdx.y, b = blockIdx.z;
    if (ti > tj) return;
    __shared__ float4 bi[64];
    __shared__ float  ai[64];
    const int lane = threadIdx.x;
    const float4* bx = boxes + (size_t)b * PRE_NMS;
    int iIdx = ti * 64 + lane;
    float4 vi0 = (iIdx < PRE_NMS) ? bx[iIdx] : make_float4(0.f, 0.f, 0.f, 0.f);
    bi[lane] = vi0;
    ai[lane] = (vi0.z - vi0.x) * (vi0.w - vi0.y);
    int j = tj * 64 + lane;
    float4 vj = (j < PRE_NMS) ? bx[j] : make_float4(0.f, 0.f, 0.f, 0.f);
    float aj = (vj.z - vj.x) * (vj.w - vj.y);
    __syncthreads();
    for (int it = 0; it < 64; ++it) {
        int i = ti * 64 + it;
        if (i < j && j < PRE_NMS) {   // i<j implies i<PRE_NMS
            float4 vi = bi[it];
            float yy1 = fmaxf(vj.x, vi.x);
            float xx1 = fmaxf(vj.y, vi.y);
            float yy2 = fminf(vj.z, vi.z);
            float xx2 = fminf(vj.w, vi.w);
            float ih = yy2 - yy1, iw = xx2 - xx1;
            if (ih > 0.f && iw > 0.f) {
                float inter = ih * iw;
                float uni = aj + ai[it] - inter;
                if (uni > 0.f && (inter / uni) > NMS_THR) {
                    unsigned pos = atomicAdd(&pcnt[b], 1u);
                    if (pos < PAIR_CAP)
                        pairs[(size_t)b * PAIR_CAP + pos] = ((unsigned)j << 13) | (unsigned)i;
                }
            }
        }
    }
}

// K6: sort pair list, sequential greedy resolve with 1000-cap, emit ranked boxes.
__global__ __launch_bounds__(256) void k_nms_emit(const uint32_t* __restrict__ pcnt,
                                                  const uint32_t* __restrict__ pairsIn,
                                                  const float4* __restrict__ boxes,
                                                  float4* __restrict__ out) {
    __shared__ uint32_t sp[PAIR_CAP];   // 32 KB
    __shared__ uint32_t rej[188];       // 6016-bit rejected bitset
    __shared__ uint32_t pre[189];
    const int b = blockIdx.x;
    unsigned np = pcnt[b]; if (np > PAIR_CAP) np = PAIR_CAP;
    const uint32_t* pb = pairsIn + (size_t)b * PAIR_CAP;
    for (int i = threadIdx.x; i < PAIR_CAP; i += 256)
        sp[i] = (i < (int)np) ? pb[i] : 0xFFFFFFFFu;
    for (int i = threadIdx.x; i < 188; i += 256) rej[i] = 0;
    __syncthreads();
    for (unsigned k = 2; k <= PAIR_CAP; k <<= 1) {
        for (unsigned j = k >> 1; j > 0; j >>= 1) {
            for (unsigned i = threadIdx.x; i < PAIR_CAP; i += 256) {
                unsigned ixj = i ^ j;
                if (ixj > i) {
                    unsigned a = sp[i], c = sp[ixj];
                    bool up = ((i & k) == 0);
                    if ((a > c) == up) { sp[i] = c; sp[ixj] = a; }
                }
            }
            __syncthreads();
        }
    }
    if (threadIdx.x == 0) {
        unsigned rejc = 0, p = 0;
        while (p < np) {
            unsigned j = sp[p] >> 13;
            if (j >= PRE_NMS) break;                 // padding
            if (j - rejc >= NPROP) break;            // cap reached before j
            bool sup = false;
            while (p < np && (sp[p] >> 13) == j) {
                unsigned i = sp[p] & 8191u;
                if (!((rej[i >> 5] >> (i & 31)) & 1u)) sup = true;
                ++p;
            }
            if (sup) { rej[j >> 5] |= (1u << (j & 31)); ++rejc; }
        }
        unsigned c2 = 0;
        for (int w = 0; w < 188; ++w) { pre[w] = c2; c2 += __popc(rej[w]); }
        pre[188] = c2;
    }
    __syncthreads();
    const float4* bx = boxes + (size_t)b * PRE_NMS;
    float4* ob = out + (size_t)b * NPROP;
    for (int j = threadIdx.x; j < PRE_NMS; j += 256) {
        unsigned w = (unsigned)j >> 5, bit = (unsigned)j & 31;
        if ((rej[w] >> bit) & 1u) continue;
        unsigned rank = (unsigned)j - (pre[w] + __popc(rej[w] & ((1u << bit) - 1u)));
        if (rank < NPROP) ob[rank] = bx[j];
    }
}

extern "C" void kernel_launch(void* const* d_in, const int* in_sizes, int n_in,
                              void* d_out, int out_size, void* d_ws, size_t ws_size,
                              hipStream_t stream) {
    const float* scores  = (const float*)d_in[0];  // (8, NA, 2)
    const float* deltas  = (const float*)d_in[1];  // (8, NA, 4)
    const float* anchors = (const float*)d_in[2];  // (NA, 4)
    float* out = (float*)d_out;                    // (8, 1000, 4)

    if (ws_size < WS_NEEDED) {
        // fail-safe: leave output poisoned rather than corrupt memory
        return;
    }

    char* ws = (char*)d_ws;
    uint32_t* hist  = (uint32_t*)ws;
    uint32_t* ccnt  = (uint32_t*)(ws + HIST_BYTES);
    uint32_t* pcnt  = ccnt + NBATCH;
    uint32_t* cbin  = pcnt + NBATCH;
    uint64_t* cand  = (uint64_t*)(ws + CAND_OFF);
    float4*   boxes = (float4*)(ws + BOXES_OFF);
    uint32_t* pairs = (uint32_t*)(ws + PAIRS_OFF);

    // zero counters (hist is fully overwritten; cbin overwritten by k_thresh)
    hipMemsetAsync((void*)ccnt, 0, 3 * NBATCH * sizeof(uint32_t), stream);
    // zero output (rows with no proposal must be 0)
    hipMemsetAsync(d_out, 0, (size_t)NBATCH * NPROP * 4 * sizeof(float), stream);

    dim3 gh(HB, NBATCH);
    k_hist<<<gh, 256, 0, stream>>>(scores, hist);
    k_thresh<<<NBATCH, 256, 0, stream>>>(hist, cbin);
    k_gather<<<gh, 256, 0, stream>>>(scores, cbin, ccnt, cand);
    k_sort_boxes<<<NBATCH, 1024, 0, stream>>>(cand, ccnt, deltas, anchors, boxes);
    dim3 gp((PRE_NMS + 63) / 64, (PRE_NMS + 63) / 64, NBATCH);
    k_pairs<<<gp, 64, 0, stream>>>(boxes, pcnt, pairs);
    k_nms_emit<<<NBATCH, 256, 0, stream>>>(pcnt, pairs, boxes, (float4*)out);
}

// Round 2
// 480.141 us; speedup vs baseline: 2.7275x; 2.7275x over previous
//
#include <hip/hip_runtime.h>
#include <stdint.h>

#define NBATCH   8
#define NA       1047552
#define PRE_NMS  6000
#define NPROP    1000
#define BINS     2048
#define HB       64         // histogram blocks per batch
#define GB       128        // gather blocks per batch
#define CAND_CAP 8192
#define NMS_THR  0.7f
#define GBUF     1024       // per-block LDS candidate buffer
#define SCAP     2048       // per-bin sort capacity
#define PCHUNK   32         // pair-list chunks per batch
#define PCAP     256        // pairs per chunk
#define REJW     188        // 6016-bit rejected bitset words

// ---- workspace layout (bytes) ----
#define OFF_HIST  ((size_t)0)                                   // 8*64*2048*2 = 2,097,152 (u16)
#define OFF_BOFF  (OFF_HIST + (size_t)NBATCH*HB*BINS*2)         // 8*2048*4 = 65,536
#define OFF_BCNT  (OFF_BOFF + (size_t)NBATCH*BINS*4)            // 65,536
#define OFF_CTR   (OFF_BCNT + (size_t)NBATCH*BINS*4)            // cbin(32)+pcnt(1024)+binpos(65536)
#define CTR_BYTES ((size_t)(32 + NBATCH*PCHUNK*4 + NBATCH*BINS*4))
#define OFF_CAND  (OFF_CTR + 66624)                             // 8*8192*8 = 524,288
#define OFF_BOXES (OFF_CAND + (size_t)NBATCH*CAND_CAP*8)        // 8*6000*16 = 768,000
#define OFF_PAIRS (OFF_BOXES + (size_t)NBATCH*PRE_NMS*16)       // 8*32*256*4 = 262,144
#define WS_NEEDED (OFF_PAIRS + (size_t)NBATCH*PCHUNK*PCAP*4)

__device__ __forceinline__ unsigned score_bin(float s) {
    int b = (int)(s * (float)BINS);
    if (b < 0) b = 0;
    if (b > BINS - 1) b = BINS - 1;
    return (unsigned)b;
}

// K1: per-block private histogram of scores[b,:,1]; store as u16 (block max 16368 fits).
__global__ __launch_bounds__(256) void k_hist(const float* __restrict__ scores,
                                              uint16_t* __restrict__ hist) {
    __shared__ uint32_t lh[BINS];
    const int b = blockIdx.y;
    for (int t = threadIdx.x; t < BINS; t += 256) lh[t] = 0;
    __syncthreads();
    const float4* s4 = reinterpret_cast<const float4*>(scores) + (size_t)b * (NA / 2);
    const int n4 = NA / 2;
    const int stride = gridDim.x * 256;
    for (int i = blockIdx.x * 256 + threadIdx.x; i < n4; i += stride) {
        float4 v = s4[i];
        atomicAdd(&lh[score_bin(v.y)], 1u);
        atomicAdd(&lh[score_bin(v.w)], 1u);
    }
    __syncthreads();
    uint16_t* gh = hist + ((size_t)b * HB + blockIdx.x) * BINS;
    for (int t = threadIdx.x; t < BINS; t += 256) gh[t] = (uint16_t)lh[t];
}

// K2: reduce hists -> per-bin counts, suffix offsets (descending bins), threshold bin C.
__global__ __launch_bounds__(256) void k_thresh(const uint16_t* __restrict__ hist,
                                                uint32_t* __restrict__ boff,
                                                uint32_t* __restrict__ bcnt,
                                                uint32_t* __restrict__ cbin) {
    __shared__ uint32_t hsum[BINS];
    __shared__ uint32_t csum[256];
    __shared__ int sC;
    const int b = blockIdx.x;
    const int t = threadIdx.x;
    if (t == 0) sC = 0;
    const uint16_t* hb = hist + (size_t)b * HB * BINS;
    uint32_t chunk = 0;
    for (int q = 0; q < 8; ++q) {
        int bin = t * 8 + q;
        uint32_t s = 0;
        for (int k = 0; k < HB; ++k) s += hb[(size_t)k * BINS + bin];
        hsum[bin] = s;
        chunk += s;
    }
    csum[t] = chunk;
    __syncthreads();
    if (t == 0) {             // suffix over 256 chunk sums (descending)
        uint32_t suf = 0;
        for (int c = 255; c >= 0; --c) { uint32_t v = csum[c]; csum[c] = suf; suf += v; }
    }
    __syncthreads();
    uint32_t acc = csum[t];   // keys in bins above this chunk
    for (int q = 7; q >= 0; --q) {
        int bin = t * 8 + q;
        uint32_t h = hsum[bin];
        boff[(size_t)b * BINS + bin] = acc;   // # keys in bins > bin
        bcnt[(size_t)b * BINS + bin] = h;
        if (acc + h >= PRE_NMS) atomicMax(&sC, bin);
        acc += h;
    }
    __syncthreads();
    if (t == 0) cbin[b] = (uint32_t)sC;
}

// K3: gather keys (bin >= C) into bin-partitioned slots via LDS block aggregation.
// key = (score_bits<<32) | ~index  (descending key order == score desc, index asc)
__global__ __launch_bounds__(256) void k_gather(const float* __restrict__ scores,
                                                const uint32_t* __restrict__ cbin,
                                                const uint32_t* __restrict__ boff,
                                                uint32_t* __restrict__ binpos,
                                                uint64_t* __restrict__ cand) {
    __shared__ uint64_t keybuf[GBUF];
    __shared__ uint16_t binbuf[GBUF];
    __shared__ uint32_t bcnts[BINS];
    __shared__ uint32_t gbase[BINS];
    __shared__ uint32_t nbuf;
    const int b = blockIdx.y;
    const unsigned C = cbin[b];
    for (int t = threadIdx.x; t < BINS; t += 256) bcnts[t] = 0;
    if (threadIdx.x == 0) nbuf = 0;
    __syncthreads();
    const float4* s4 = reinterpret_cast<const float4*>(scores) + (size_t)b * (NA / 2);
    const int n4 = NA / 2;
    const int stride = gridDim.x * 256;
    uint64_t* cb = cand + (size_t)b * CAND_CAP;
    for (int i = blockIdx.x * 256 + threadIdx.x; i < n4; i += stride) {
        float4 v = s4[i];
        float sc[2] = { v.y, v.w };
        #pragma unroll
        for (int h = 0; h < 2; ++h) {
            unsigned bin = score_bin(sc[h]);
            if (bin >= C) {
                unsigned idx = 2u * (unsigned)i + (unsigned)h;
                uint64_t key = ((uint64_t)__float_as_uint(sc[h]) << 32) | (uint32_t)(~idx);
                unsigned p = atomicAdd(&nbuf, 1u);
                if (p < GBUF) {
                    keybuf[p] = key; binbuf[p] = (uint16_t)bin;
                    atomicAdd(&bcnts[bin], 1u);
                } else {  // overflow fallback: direct global placement (slow path, rare)
                    unsigned pos = boff[(size_t)b * BINS + bin] +
                                   atomicAdd(&binpos[(size_t)b * BINS + bin], 1u);
                    if (pos < CAND_CAP) cb[pos] = key;
                }
            }
        }
    }
    __syncthreads();
    for (int t = threadIdx.x; t < BINS; t += 256) {
        uint32_t c = bcnts[t];
        if (c) gbase[t] = boff[(size_t)b * BINS + t] +
                          atomicAdd(&binpos[(size_t)b * BINS + t], c);
        bcnts[t] = 0;   // reuse as intra-bin cursor
    }
    __syncthreads();
    unsigned n = nbuf; if (n > GBUF) n = GBUF;
    for (unsigned p = threadIdx.x; p < n; p += 256) {
        unsigned bn = binbuf[p];
        unsigned pos = gbase[bn] + atomicAdd(&bcnts[bn], 1u);
        if (pos < CAND_CAP) cb[pos] = keybuf[p];
    }
}

// K4: per-(batch,bin) bitonic sort of its segment (descending keys), in place.
__global__ __launch_bounds__(256) void k_binsort(const uint32_t* __restrict__ cbin,
                                                 const uint32_t* __restrict__ boff,
                                                 const uint32_t* __restrict__ bcnt,
                                                 uint64_t* __restrict__ cand) {
    __shared__ uint64_t s[SCAP];   // 16 KB
    const int b = blockIdx.y;
    const unsigned bin = cbin[b] + blockIdx.x;
    if (bin >= BINS) return;
    unsigned cnt = bcnt[(size_t)b * BINS + bin];
    if (cnt == 0) return;
    unsigned start = boff[(size_t)b * BINS + bin];
    if (start >= CAND_CAP) return;
    if (start + cnt > CAND_CAP) cnt = CAND_CAP - start;
    if (cnt > SCAP) cnt = SCAP;  // envelope guard (expected ~512/bin)
    uint64_t* seg = cand + (size_t)b * CAND_CAP + start;
    for (unsigned i = threadIdx.x; i < SCAP; i += 256)
        s[i] = (i < cnt) ? ~seg[i] : ~0ull;    // ascending ~key == descending key; pad last
    __syncthreads();
    for (unsigned k = 2; k <= SCAP; k <<= 1) {
        for (unsigned j = k >> 1; j > 0; j >>= 1) {
            for (unsigned i = threadIdx.x; i < SCAP; i += 256) {
                unsigned ixj = i ^ j;
                if (ixj > i) {
                    uint64_t a = s[i], c = s[ixj];
                    bool up = ((i & k) == 0);
                    if ((a > c) == up) { s[i] = c; s[ixj] = a; }
                }
            }
            __syncthreads();
        }
    }
    for (unsigned i = threadIdx.x; i < cnt; i += 256) seg[i] = ~s[i];
}

// K5: decode boxes for global ranks 0..PRE_NMS-1 (array is fully sorted across bins).
__global__ __launch_bounds__(256) void k_decode(const uint64_t* __restrict__ cand,
                                                const float* __restrict__ deltas,
                                                const float* __restrict__ anchors,
                                                float4* __restrict__ boxesOut) {
    const int b = blockIdx.y;
    const int r = blockIdx.x * 256 + threadIdx.x;
    if (r >= PRE_NMS) return;
    uint64_t key = cand[(size_t)b * CAND_CAP + r];
    unsigned idx = ~(uint32_t)key;
    float4 o = make_float4(0.f, 0.f, 0.f, 0.f);
    if (idx < NA) {
        float4 a = reinterpret_cast<const float4*>(anchors)[idx];
        float4 d = reinterpret_cast<const float4*>(deltas)[(size_t)b * NA + idx];
        float h = a.z - a.x, w = a.w - a.y;
        float cy = a.x + 0.5f * h + (d.x * 0.1f) * h;
        float cx = a.y + 0.5f * w + (d.y * 0.1f) * w;
        h = h * expf(d.z * 0.2f);
        w = w * expf(d.w * 0.2f);
        float y1 = cy - 0.5f * h, x1 = cx - 0.5f * w;
        float y2 = y1 + h,        x2 = x1 + w;
        o.x = fminf(fmaxf(y1, 0.f), 1.f);
        o.y = fminf(fmaxf(x1, 0.f), 1.f);
        o.z = fminf(fmaxf(y2, 0.f), 1.f);
        o.w = fminf(fmaxf(x2, 0.f), 1.f);
    }
    boxesOut[(size_t)b * PRE_NMS + r] = o;
}

// K6: sparse overlap pairs (i<j, IoU>thr), scattered into 32 chunks to spread atomics.
__global__ __launch_bounds__(64) void k_pairs(const float4* __restrict__ boxes,
                                              uint32_t* __restrict__ pcnt,
                                              uint32_t* __restrict__ pairs) {
    const int tj = blockIdx.x, ti = blockIdx.y, b = blockIdx.z;
    if (ti > tj) return;
    __shared__ float4 bi[64];
    __shared__ float  ai[64];
    const int lane = threadIdx.x;
    const float4* bx = boxes + (size_t)b * PRE_NMS;
    int iIdx = ti * 64 + lane;
    float4 vi0 = (iIdx < PRE_NMS) ? bx[iIdx] : make_float4(0.f, 0.f, 0.f, 0.f);
    bi[lane] = vi0;
    ai[lane] = (vi0.z - vi0.x) * (vi0.w - vi0.y);
    int j = tj * 64 + lane;
    float4 vj = (j < PRE_NMS) ? bx[j] : make_float4(0.f, 0.f, 0.f, 0.f);
    float aj = (vj.z - vj.x) * (vj.w - vj.y);
    __syncthreads();
    for (int it = 0; it < 64; ++it) {
        int i = ti * 64 + it;
        if (i < j && j < PRE_NMS) {
            float4 vi = bi[it];
            float yy1 = fmaxf(vj.x, vi.x);
            float xx1 = fmaxf(vj.y, vi.y);
            float yy2 = fminf(vj.z, vi.z);
            float xx2 = fminf(vj.w, vi.w);
            float ih = yy2 - yy1, iw = xx2 - xx1;
            if (ih > 0.f && iw > 0.f) {
                float inter = ih * iw;
                float uni = aj + ai[it] - inter;
                if (uni > 0.f && (inter / uni) > NMS_THR) {
                    unsigned c = ((unsigned)i + (unsigned)j) & (PCHUNK - 1);
                    unsigned pos = atomicAdd(&pcnt[b * PCHUNK + c], 1u);
                    if (pos < PCAP)
                        pairs[((size_t)b * PCHUNK + c) * PCAP + pos] =
                            ((unsigned)j << 13) | (unsigned)i;
                }
            }
        }
    }
}

// K7: Jacobi fixpoint greedy-NMS resolve on the sparse pair list + ranked emit.
// rej_next[j] = OR over pairs(i,j) of !rej_cur[i]; any fixpoint == greedy answer.
__global__ __launch_bounds__(256) void k_nms_emit(const uint32_t* __restrict__ pcnt,
                                                  const uint32_t* __restrict__ pairsIn,
                                                  const float4* __restrict__ boxes,
                                                  float4* __restrict__ out) {
    __shared__ uint32_t sp[PCHUNK * PCAP];   // 32 KB
    __shared__ uint32_t cpref[PCHUNK + 1];
    __shared__ uint32_t rejA[REJW], rejB[REJW], pre[REJW + 1];
    __shared__ int changed;
    const int b = blockIdx.x;
    const int tid = threadIdx.x;
    if (tid == 0) {
        unsigned s = 0;
        for (int c = 0; c < PCHUNK; ++c) {
            cpref[c] = s;
            unsigned cc = pcnt[b * PCHUNK + c];
            if (cc > PCAP) cc = PCAP;
            s += cc;
        }
        cpref[PCHUNK] = s;
    }
    for (int t = tid; t < REJW; t += 256) rejA[t] = 0;
    __syncthreads();
    const unsigned np = cpref[PCHUNK];
    for (int c = 0; c < PCHUNK; ++c) {
        unsigned cnt = cpref[c + 1] - cpref[c];
        for (unsigned k = tid; k < cnt; k += 256)
            sp[cpref[c] + k] = pairsIn[((size_t)b * PCHUNK + c) * PCAP + k];
    }
    __syncthreads();
    for (int iter = 0; iter < PRE_NMS; ++iter) {
        for (int t = tid; t < REJW; t += 256) rejB[t] = 0;
        if (tid == 0) changed = 0;
        __syncthreads();
        for (unsigned p = tid; p < np; p += 256) {
            unsigned u = sp[p];
            unsigned j = u >> 13, i = u & 8191u;
            if (!((rejA[i >> 5] >> (i & 31)) & 1u))
                atomicOr(&rejB[j >> 5], 1u << (j & 31));
        }
        __syncthreads();
        for (int t = tid; t < REJW; t += 256) {
            if (rejB[t] != rejA[t]) changed = 1;
            rejA[t] = rejB[t];
        }
        __syncthreads();
        if (!changed) break;
    }
    if (tid == 0) {
        unsigned c2 = 0;
        for (int w = 0; w < REJW; ++w) { pre[w] = c2; c2 += __popc(rejA[w]); }
        pre[REJW] = c2;
    }
    __syncthreads();
    const float4* bx = boxes + (size_t)b * PRE_NMS;
    float4* ob = out + (size_t)b * NPROP;
    for (int j = tid; j < PRE_NMS; j += 256) {
        unsigned w = (unsigned)j >> 5, bit = (unsigned)j & 31;
        if ((rejA[w] >> bit) & 1u) continue;
        unsigned rank = (unsigned)j - (pre[w] + __popc(rejA[w] & ((1u << bit) - 1u)));
        if (rank < NPROP) ob[rank] = bx[j];
    }
}

extern "C" void kernel_launch(void* const* d_in, const int* in_sizes, int n_in,
                              void* d_out, int out_size, void* d_ws, size_t ws_size,
                              hipStream_t stream) {
    const float* scores  = (const float*)d_in[0];  // (8, NA, 2)
    const float* deltas  = (const float*)d_in[1];  // (8, NA, 4)
    const float* anchors = (const float*)d_in[2];  // (NA, 4)

    if (ws_size < WS_NEEDED) return;  // fail-safe

    char* ws = (char*)d_ws;
    uint16_t* hist   = (uint16_t*)(ws + OFF_HIST);
    uint32_t* boff   = (uint32_t*)(ws + OFF_BOFF);
    uint32_t* bcnt   = (uint32_t*)(ws + OFF_BCNT);
    uint32_t* cbin   = (uint32_t*)(ws + OFF_CTR);
    uint32_t* pcnt   = cbin + NBATCH;
    uint32_t* binpos = pcnt + NBATCH * PCHUNK;
    uint64_t* cand   = (uint64_t*)(ws + OFF_CAND);
    float4*   boxes  = (float4*)(ws + OFF_BOXES);
    uint32_t* pairs  = (uint32_t*)(ws + OFF_PAIRS);

    // zero counters (cbin+pcnt+binpos contiguous) and output
    hipMemsetAsync((void*)cbin, 0, CTR_BYTES, stream);
    hipMemsetAsync(d_out, 0, (size_t)NBATCH * NPROP * 4 * sizeof(float), stream);

    k_hist   <<<dim3(HB, NBATCH), 256, 0, stream>>>(scores, hist);
    k_thresh <<<NBATCH, 256, 0, stream>>>(hist, boff, bcnt, cbin);
    k_gather <<<dim3(GB, NBATCH), 256, 0, stream>>>(scores, cbin, boff, binpos, cand);
    k_binsort<<<dim3(128, NBATCH), 256, 0, stream>>>(cbin, boff, bcnt, cand);
    k_decode <<<dim3((PRE_NMS + 255) / 256, NBATCH), 256, 0, stream>>>(cand, deltas, anchors, boxes);
    k_pairs  <<<dim3((PRE_NMS + 63) / 64, (PRE_NMS + 63) / 64, NBATCH), 64, 0, stream>>>(boxes, pcnt, pairs);
    k_nms_emit<<<NBATCH, 256, 0, stream>>>(pcnt, pairs, boxes, (float4*)d_out);
}